// Round 13
// baseline (202.792 us; speedup 1.0000x reference)
//
#include <hip/hip_runtime.h>

// WordSAGE on MI355X — fp32 in/out. Round-13:
//   k_prep : fused [XCD-private edge fillpad (CAP8=32 -> one 64B line/slot) |
//            train->AF | gene->GH | W pack]
//   k_mega : phase0 gather rewritten WAVE-UNIFORM (1 wave = 1 row at a time,
//            64 lanes = 128 feats, scalar edge idx, coalesced GH reads, no
//            divergence) -- round-12 post-mortem: divergent 8-segment walk was
//            ~25us of mega's 48. Tiles XCD-swizzled so AF reads hit the L2
//            of the XCD that wrote them. Activations hi-only; weights hi+lo.

#define NG 2500
#define NT 20000
#define NE 640000
#define NCLS 16
#define CAP8 32      // per-XCD per-dst cap = exactly one 64B line
#define NTILE 1250   // NT/16

typedef unsigned short u16;
typedef unsigned int u32;

typedef float f32x4 __attribute__((ext_vector_type(4)));
typedef __bf16 bf16x8 __attribute__((ext_vector_type(8)));

__device__ __forceinline__ float b2f(u16 u) { return __uint_as_float(((u32)u) << 16); }
__device__ __forceinline__ float blo(u32 p) { return __uint_as_float(p << 16); }
__device__ __forceinline__ float bhi(u32 p) { return __uint_as_float(p & 0xffff0000u); }
__device__ __forceinline__ u16 f2b(float f) {  // RNE fp32->bf16
    u32 u = __float_as_uint(f);
    return (u16)((u + 0x7fffu + ((u >> 16) & 1u)) >> 16);
}

// ---- sizes ---------------------------------------------------------------
#define B1N 81920
#define B2N 32768
#define B3N 16384
#define B4N 2048
#define NEB 2500
#define CVB NTILE
#define GNB 625
#define PKB 520

// ---- fused prep -----------------------------------------------------------
__global__ __launch_bounds__(256) void k_prep(
    const int* __restrict__ esrc, const int* __restrict__ edst,
    int* __restrict__ cnt8, u16* __restrict__ csr8,
    const float* __restrict__ train, const float* __restrict__ gene,
    u16* __restrict__ AF, u32* __restrict__ GH32,
    const float* __restrict__ W1n, const float* __restrict__ W1s,
    const float* __restrict__ W2n, const float* __restrict__ W2s,
    const float* __restrict__ Wc1, const float* __restrict__ Wc2,
    u16* __restrict__ B1h, u16* __restrict__ B1l,
    u16* __restrict__ B2h, u16* __restrict__ B2l,
    u16* __restrict__ B3h, u16* __restrict__ B3l,
    u16* __restrict__ B4h, u16* __restrict__ B4l) {
    int blk = blockIdx.x, t = threadIdx.x;
    if (blk < NEB) {
        int xcc = __builtin_amdgcn_s_getreg(63508) & 7;  // HW_REG_XCC_ID
        int* mycnt = cnt8 + (size_t)xcc * NT;
        u16* mycsr = csr8 + (size_t)xcc * NT * CAP8;
        int e = blk * 256 + t;
        if (e < NE) {
            unsigned d = (unsigned)edst[e];
            if (d < NT) {
                int slot = atomicAdd(&mycnt[d], 1);
                if (slot < CAP8) mycsr[(size_t)d * CAP8 + slot] = (u16)esrc[e];
            }
        }
        return;
    }
    if (blk < NEB + CVB) {
        __shared__ __align__(16) u16 L[16 * 520];
        u32* L32 = (u32*)L;
        int tile = blk - NEB;
        for (int i = t; i < 160; i += 256) {
            int r = i / 10, c = i - r * 10;
            L32[r * 260 + 250 + c] = 0;
        }
        for (int i = t; i < 2000; i += 256) {
            int r = i / 125, c4 = i - r * 125;
            float4 v = *(const float4*)(train + (size_t)(tile * 16 + r) * 500 + c4 * 4);
            int base = r * 260 + c4 * 2;
            L32[base] = (u32)f2b(v.x) | ((u32)f2b(v.y) << 16);
            L32[base + 1] = (u32)f2b(v.z) | ((u32)f2b(v.w) << 16);
        }
        __syncthreads();
#pragma unroll
        for (int it = 0; it < 4; ++it) {
            int slot = t + it * 256;
            int kk = slot >> 6, lane = slot & 63;
            int m = lane & 15, q = lane >> 4;
            uint4 v = *(const uint4*)(L + m * 520 + kk * 32 + q * 8);
            *(uint4*)(AF + (((size_t)tile * 16 + kk) * 64 + lane) * 8) = v;
        }
        return;
    }
    if (blk < NEB + CVB + GNB) {
        int idx = (blk - NEB - CVB) * 256 + t;
        float2 v = ((const float2*)gene)[idx];
        GH32[idx] = (u32)f2b(v.x) | ((u32)f2b(v.y) << 16);
        return;
    }
    int idx = (blk - NEB - CVB - GNB) * 256 + t;
    float v = 0.f;
    u16 *ph = 0, *pl = 0;
    int off = 0;
    if (idx < B1N) {
        int j = idx & 7, l = (idx >> 3) & 63, rest = idx >> 9;
        int g = rest & 7, kk = rest >> 3;
        int k = kk * 32 + ((l >> 4) << 3) + j, n = (g << 4) + (l & 15);
        if (k < 500) v = W1s[k * 128 + n];
        else if (k >= 512) v = W1n[(k - 512) * 128 + n];
        ph = B1h; pl = B1l; off = idx;
    } else if (idx < B1N + B2N) {
        int e = idx - B1N;
        int j = e & 7, l = (e >> 3) & 63, rest = e >> 9;
        int g = rest & 7, kk = rest >> 3;
        int k = kk * 32 + ((l >> 4) << 3) + j, n = (g << 4) + (l & 15);
        v = (k < 128) ? W2s[k * 128 + n] : W2n[(k - 128) * 128 + n];
        ph = B2h; pl = B2l; off = e;
    } else if (idx < B1N + B2N + B3N) {
        int e = idx - (B1N + B2N);
        int j = e & 7, l = (e >> 3) & 63, rest = e >> 9;
        int g = rest & 7, kk = rest >> 3;
        int k = kk * 32 + ((l >> 4) << 3) + j, n = (g << 4) + (l & 15);
        v = Wc1[k * 128 + n];
        ph = B3h; pl = B3l; off = e;
    } else if (idx < B1N + B2N + B3N + B4N) {
        int e = idx - (B1N + B2N + B3N);
        int j = e & 7, l = (e >> 3) & 63, kk = e >> 9;
        int k = kk * 32 + ((l >> 4) << 3) + j, n = l & 15;
        v = Wc2[k * 16 + n];
        ph = B4h; pl = B4l; off = e;
    }
    if (ph) {
        u16 hi = f2b(v);
        u16 lo = f2b(v - b2f(hi));
        ph[off] = hi;
        pl[off] = lo;
    }
}

// ---- fused gather + 4-layer MFMA ------------------------------------------
// Block: 512 thr (8 waves). Tiles XCD-swizzled: block b (XCD b%8) takes tiles
// of class t%8 == (b+4)%8, which prep block NEB+t (XCD (t+4)%8) wrote.
__global__ __launch_bounds__(512) void k_mega(
    const int* __restrict__ cnt8, const u16* __restrict__ csr8,
    const u16* __restrict__ GH, const u16* __restrict__ AF,
    const u16* __restrict__ B1h, const u16* __restrict__ B1l,
    const u16* __restrict__ B2h, const u16* __restrict__ B2l,
    const u16* __restrict__ B3h, const u16* __restrict__ B3l,
    const u16* __restrict__ B4h, const u16* __restrict__ B4l,
    const float* __restrict__ b1, const float* __restrict__ b2,
    const float* __restrict__ bc1, const float* __restrict__ bc2,
    float* __restrict__ out) {
    __shared__ __align__(16) u16 SAGh[32 * 136];
    __shared__ __align__(16) u16 S1h[32 * 136];
    __shared__ __align__(16) u16 S2h[32 * 136];
    int t = threadIdx.x;
    int lane = t & 63, w = t >> 6;  // wave 0..7

    // tile swizzle (bijection over 1250 tiles, 625 blocks x 2)
    int b = blockIdx.x;
    int t0, t1;
    if (b < 616) {
        int k = (b + 4) & 7;
        int j = (b >> 3) * 2;
        t0 = k + 8 * j;
        t1 = t0 + 8;
    } else {
        t0 = 1232 + 2 * (b - 616);
        t1 = t0 + 1;
    }
    int grow0 = t0 * 16, grow1 = t1 * 16;
    const u32* GH32 = (const u32*)GH;

    // ---- phase 0: wave-uniform gather-mean (1 wave = 1 row, 4 rows/wave) ----
    {
        u32* SH = (u32*)SAGh;
#pragma unroll
        for (int i = 0; i < 4; ++i) {
            int r = w * 4 + i;                      // LDS row 0..31
            int d = (r < 16) ? grow0 + r : grow1 + (r - 16);
            float a0 = 0.f, a1 = 0.f;
            int ctot = 0;
            for (int x = 0; x < 8; ++x) {
                int craw = cnt8[x * NT + d];
                ctot += craw;
                int c = craw > CAP8 ? CAP8 : craw;
                const u16* crow = csr8 + ((size_t)x * NT + d) * CAP8;
                int j = 0;
                for (; j + 1 < c; j += 2) {
                    int s0 = crow[j], s1 = crow[j + 1];
                    u32 p0 = GH32[s0 * 64 + lane];
                    u32 p1 = GH32[s1 * 64 + lane];
                    a0 += blo(p0) + blo(p1);
                    a1 += bhi(p0) + bhi(p1);
                }
                if (j < c) {
                    int s = crow[j];
                    u32 p = GH32[s * 64 + lane];
                    a0 += blo(p);
                    a1 += bhi(p);
                }
            }
            float inv = (ctot > 0) ? 1.f / (float)ctot : 0.f;
            a0 *= inv; a1 *= inv;
            SH[r * 68 + lane] = (u32)f2b(a0) | ((u32)f2b(a1) << 16);
        }
    }
    __syncthreads();

    int g = w;  // wave = col-group 0..7
    int m = lane & 15, q = lane >> 4, n16 = lane & 15;

    const u16* aB0 = AF + (((size_t)t0 * 16) * 64 + lane) * 8;  // +512/kk
    const u16* aB1 = AF + (((size_t)t1 * 16) * 64 + lane) * 8;  // +512/kk
    int hr0 = m * 136 + q * 8;
    int hr1 = (16 + m) * 136 + q * 8;
    int cr0 = q * 4;
    const f32x4 z4 = {0.f, 0.f, 0.f, 0.f};
    f32x4 acc0 = z4, acc1 = z4;

    // ---- layer1: K=640 (train kk0..15 global; agg kk16..19 LDS) ----
#pragma unroll 4
    for (int kk = 0; kk < 16; ++kk) {
        bf16x8 a0 = *(const bf16x8*)(aB0 + kk * 512);
        bf16x8 a1 = *(const bf16x8*)(aB1 + kk * 512);
        size_t bo = ((size_t)(kk * 8 + g) * 64 + lane) * 8;
        bf16x8 bh = *(const bf16x8*)(B1h + bo);
        bf16x8 bl = *(const bf16x8*)(B1l + bo);
        acc0 = __builtin_amdgcn_mfma_f32_16x16x32_bf16(a0, bh, acc0, 0, 0, 0);
        acc0 = __builtin_amdgcn_mfma_f32_16x16x32_bf16(a0, bl, acc0, 0, 0, 0);
        acc1 = __builtin_amdgcn_mfma_f32_16x16x32_bf16(a1, bh, acc1, 0, 0, 0);
        acc1 = __builtin_amdgcn_mfma_f32_16x16x32_bf16(a1, bl, acc1, 0, 0, 0);
    }
#pragma unroll
    for (int kk = 16; kk < 20; ++kk) {
        int o = (kk - 16) * 32;
        bf16x8 ah0 = *(const bf16x8*)(SAGh + hr0 + o);
        bf16x8 ah1 = *(const bf16x8*)(SAGh + hr1 + o);
        size_t bo = ((size_t)(kk * 8 + g) * 64 + lane) * 8;
        bf16x8 bh = *(const bf16x8*)(B1h + bo);
        bf16x8 bl = *(const bf16x8*)(B1l + bo);
        acc0 = __builtin_amdgcn_mfma_f32_16x16x32_bf16(ah0, bh, acc0, 0, 0, 0);
        acc0 = __builtin_amdgcn_mfma_f32_16x16x32_bf16(ah0, bl, acc0, 0, 0, 0);
        acc1 = __builtin_amdgcn_mfma_f32_16x16x32_bf16(ah1, bh, acc1, 0, 0, 0);
        acc1 = __builtin_amdgcn_mfma_f32_16x16x32_bf16(ah1, bl, acc1, 0, 0, 0);
    }
    {
        int n = g * 16 + n16;
        float bias = b1[n];
#pragma unroll
        for (int rg = 0; rg < 4; ++rg) {
            float v0 = acc0[rg] + bias; v0 = v0 > 0.f ? v0 : 0.f;
            float v1 = acc1[rg] + bias; v1 = v1 > 0.f ? v1 : 0.f;
            S1h[(cr0 + rg) * 136 + n] = f2b(v0);
            S1h[(16 + cr0 + rg) * 136 + n] = f2b(v1);
        }
    }
    __syncthreads();

    // ---- layer2: K=256 (h1 kk0..3 S1; agg kk4..7 SAG) ----
    acc0 = z4; acc1 = z4;
#pragma unroll
    for (int kk = 0; kk < 8; ++kk) {
        const u16* Ph = (kk < 4) ? S1h : SAGh;
        int o = (kk & 3) * 32;
        bf16x8 ah0 = *(const bf16x8*)(Ph + hr0 + o);
        bf16x8 ah1 = *(const bf16x8*)(Ph + hr1 + o);
        size_t bo = ((size_t)(kk * 8 + g) * 64 + lane) * 8;
        bf16x8 bh = *(const bf16x8*)(B2h + bo);
        bf16x8 bl = *(const bf16x8*)(B2l + bo);
        acc0 = __builtin_amdgcn_mfma_f32_16x16x32_bf16(ah0, bh, acc0, 0, 0, 0);
        acc0 = __builtin_amdgcn_mfma_f32_16x16x32_bf16(ah0, bl, acc0, 0, 0, 0);
        acc1 = __builtin_amdgcn_mfma_f32_16x16x32_bf16(ah1, bh, acc1, 0, 0, 0);
        acc1 = __builtin_amdgcn_mfma_f32_16x16x32_bf16(ah1, bl, acc1, 0, 0, 0);
    }
    {
        int n = g * 16 + n16;
        float bias = b2[n];
#pragma unroll
        for (int rg = 0; rg < 4; ++rg) {
            float v0 = acc0[rg] + bias; v0 = v0 > 0.f ? v0 : 0.f;
            float v1 = acc1[rg] + bias; v1 = v1 > 0.f ? v1 : 0.f;
            S2h[(cr0 + rg) * 136 + n] = f2b(v0);
            S2h[(16 + cr0 + rg) * 136 + n] = f2b(v1);
        }
    }
    __syncthreads();

    // ---- layer3: K=128 (h2 S2) -> S1 ----
    acc0 = z4; acc1 = z4;
#pragma unroll
    for (int kk = 0; kk < 4; ++kk) {
        int o = kk * 32;
        bf16x8 ah0 = *(const bf16x8*)(S2h + hr0 + o);
        bf16x8 ah1 = *(const bf16x8*)(S2h + hr1 + o);
        size_t bo = ((size_t)(kk * 8 + g) * 64 + lane) * 8;
        bf16x8 bh = *(const bf16x8*)(B3h + bo);
        bf16x8 bl = *(const bf16x8*)(B3l + bo);
        acc0 = __builtin_amdgcn_mfma_f32_16x16x32_bf16(ah0, bh, acc0, 0, 0, 0);
        acc0 = __builtin_amdgcn_mfma_f32_16x16x32_bf16(ah0, bl, acc0, 0, 0, 0);
        acc1 = __builtin_amdgcn_mfma_f32_16x16x32_bf16(ah1, bh, acc1, 0, 0, 0);
        acc1 = __builtin_amdgcn_mfma_f32_16x16x32_bf16(ah1, bl, acc1, 0, 0, 0);
    }
    {
        int n = g * 16 + n16;
        float bias = bc1[n];
#pragma unroll
        for (int rg = 0; rg < 4; ++rg) {
            float v0 = acc0[rg] + bias; v0 = v0 > 0.f ? v0 : 0.f;
            float v1 = acc1[rg] + bias; v1 = v1 > 0.f ? v1 : 0.f;
            S1h[(cr0 + rg) * 136 + n] = f2b(v0);
            S1h[(16 + cr0 + rg) * 136 + n] = f2b(v1);
        }
    }
    __syncthreads();

    // ---- layer4: K=128, N=16 (waves 0,1 = tiles t0,t1) ----
    if (g < 2) {
        int hr = (g == 0) ? hr0 : hr1;
        int growx = (g == 0) ? grow0 : grow1;
        f32x4 a4 = z4;
#pragma unroll
        for (int kk = 0; kk < 4; ++kk) {
            bf16x8 ah = *(const bf16x8*)(S1h + hr + kk * 32);
            size_t bo = ((size_t)kk * 64 + lane) * 8;
            bf16x8 bh = *(const bf16x8*)(B4h + bo);
            bf16x8 bl = *(const bf16x8*)(B4l + bo);
            a4 = __builtin_amdgcn_mfma_f32_16x16x32_bf16(ah, bh, a4, 0, 0, 0);
            a4 = __builtin_amdgcn_mfma_f32_16x16x32_bf16(ah, bl, a4, 0, 0, 0);
        }
        float bias = bc2[n16];
#pragma unroll
        for (int rg = 0; rg < 4; ++rg)
            out[(size_t)(growx + cr0 + rg) * NCLS + n16] = a4[rg] + bias;
    }
}

extern "C" void kernel_launch(void* const* d_in, const int* in_sizes, int n_in,
                              void* d_out, int out_size, void* d_ws, size_t ws_size,
                              hipStream_t stream) {
    const float* gene = (const float*)d_in[0];
    const float* train = (const float*)d_in[1];
    const int* esrc = (const int*)d_in[2];
    const int* edst = (const int*)d_in[3];

    char* ws = (char*)d_ws;
    int* cnt8 = (int*)(ws + 0);             //    640000 (8 x NT)
    u16* csr8 = (u16*)(ws + 640000);        //  10240000 (8 x NT x 32 u16)
    u16* AF = (u16*)(ws + 10880000);        //  20480000
    u16* GH = (u16*)(ws + 31360000);        //    640000
    u16* B1h = (u16*)(ws + 32000000);       //    163840
    u16* B1l = (u16*)(ws + 32163840);       //    163840
    u16* B2h = (u16*)(ws + 32327680);       //     65536
    u16* B2l = (u16*)(ws + 32393216);       //     65536
    u16* B3h = (u16*)(ws + 32458752);       //     32768
    u16* B3l = (u16*)(ws + 32491520);       //     32768
    u16* B4h = (u16*)(ws + 32524288);       //      4096
    u16* B4l = (u16*)(ws + 32528384);       //      4096
    // total 32,532,480 B

    hipMemsetAsync(cnt8, 0, 8 * NT * sizeof(int), stream);
    k_prep<<<NEB + CVB + GNB + PKB, 256, 0, stream>>>(
        esrc, edst, cnt8, csr8, train, gene, AF, (u32*)GH,
        (const float*)d_in[4], (const float*)d_in[5], (const float*)d_in[7],
        (const float*)d_in[8], (const float*)d_in[10], (const float*)d_in[12],
        B1h, B1l, B2h, B2l, B3h, B3l, B4h, B4l);
    k_mega<<<625, 512, 0, stream>>>(
        cnt8, csr8, GH, AF, B1h, B1l, B2h, B2l, B3h, B3l, B4h, B4l,
        (const float*)d_in[6], (const float*)d_in[9], (const float*)d_in[11],
        (const float*)d_in[13], (float*)d_out);
}